// Round 11
// baseline (339.320 us; speedup 1.0000x reference)
//
#include <hip/hip_runtime.h>
#include <math.h>

// ---------------------------------------------------------------------------
// B=64 graphs, NN=133 nodes. 9 plain launches:
//  K1 prep_emb : blocks<399 -> emb GEMM tiles; blocks>=399 -> sparse prep
//  K2 gemm1 t1=h0@gc1_w (532 tiles)
//  K3 spmm1 y1 (GRP=4, 1 wave/row)       K4 pool1 p1 (GRP=4)
//  K5 gemm2 t2=p1@gc2_w (266)
//  K6 twohop2: p2[r,c]=max_{j in front(r)} relu(b_c+sum_k a_jk t2[k,c])
//     (replaces spmm2+pool2 — no y2 materialization, same 8512-wave shape)
//  K7 gemm3 t3=p2@gc3_w (266)
//  K8 twohop3+t4: t4[r]=sum_c p3[r,c]*gc4_w[c], p3 two-hop in registers
//     (replaces spmm3+pool3+t4)
//  K9 tail: y4 sparse from t4 + fc1 + fin -> sigmoid (64 blocks)
// Sparse lists per row: front = a>1e-5 (spmm+pool), back = 0<a<=1e-5 (spmm
// only). All sparse kernels: one wave per adjacency row; pair lists read as
// float4 (2 pairs) -> independent gather chains in flight.
// ---------------------------------------------------------------------------

#define NN 133
#define NPAIR 64

// ---------------- GEMM core: one 64x64 tile, prefetch-pipelined -------------
template<int VECA, int VECB, int RELU, int BIAS>
__device__ __forceinline__ void gemm_tile_core(
    const float* __restrict__ A, int lda, int K,
    const float* __restrict__ W, int N,
    const float* __restrict__ bias,
    float* __restrict__ C, int ldc, int padN,
    int m0, int n0, float (*As)[68], float (*Bs)[68], int tid)
{
    const int la_m = tid >> 2, la_k = (tid & 3) * 4;   // A: 64 rows x 4 float4
    const int lb_k = tid >> 4, lb_n = (tid & 15) * 4;  // B: 16 k-rows x 16 f4
    const int tx = tid & 15, ty = tid >> 4;
    const int r = m0 + la_m;

    float pa[4], pb[4];
    if (VECA) {
        float4 v = *reinterpret_cast<const float4*>(A + (size_t)r * lda + la_k);
        pa[0] = v.x; pa[1] = v.y; pa[2] = v.z; pa[3] = v.w;
    } else {
#pragma unroll
        for (int j = 0; j < 4; ++j) {
            int gk = la_k + j;
            pa[j] = (gk < K) ? A[(size_t)r * lda + gk] : 0.f;
        }
    }
    if (VECB) {
        if (lb_k < K) {
            float4 v = *reinterpret_cast<const float4*>(
                W + (size_t)lb_k * N + n0 + lb_n);
            pb[0] = v.x; pb[1] = v.y; pb[2] = v.z; pb[3] = v.w;
        } else { pb[0] = pb[1] = pb[2] = pb[3] = 0.f; }
    } else {
#pragma unroll
        for (int j = 0; j < 4; ++j) {
            int gn = n0 + lb_n + j;
            pb[j] = (lb_k < K && gn < N) ? W[(size_t)lb_k * N + gn] : 0.f;
        }
    }

    float acc[4][4] = {};
    for (int k0 = 0; k0 < K; k0 += 16) {
        __syncthreads();
#pragma unroll
        for (int j = 0; j < 4; ++j) As[la_k + j][la_m] = pa[j];
        *reinterpret_cast<float4*>(&Bs[lb_k][lb_n]) =
            make_float4(pb[0], pb[1], pb[2], pb[3]);
        __syncthreads();
        const int kn = k0 + 16;
        if (kn < K) {   // prefetch next k-tile (overlaps FMA block)
            if (VECA) {
                float4 v = *reinterpret_cast<const float4*>(
                    A + (size_t)r * lda + kn + la_k);
                pa[0] = v.x; pa[1] = v.y; pa[2] = v.z; pa[3] = v.w;
            } else {
#pragma unroll
                for (int j = 0; j < 4; ++j) {
                    int gk = kn + la_k + j;
                    pa[j] = (gk < K) ? A[(size_t)r * lda + gk] : 0.f;
                }
            }
            int gk = kn + lb_k;
            if (VECB) {
                if (gk < K) {
                    float4 v = *reinterpret_cast<const float4*>(
                        W + (size_t)gk * N + n0 + lb_n);
                    pb[0] = v.x; pb[1] = v.y; pb[2] = v.z; pb[3] = v.w;
                } else { pb[0] = pb[1] = pb[2] = pb[3] = 0.f; }
            } else {
#pragma unroll
                for (int j = 0; j < 4; ++j) {
                    int gn = n0 + lb_n + j;
                    pb[j] = (gk < K && gn < N) ? W[(size_t)gk * N + gn] : 0.f;
                }
            }
        }
#pragma unroll
        for (int k = 0; k < 16; ++k) {
            float4 av = *reinterpret_cast<const float4*>(&As[k][ty * 4]);
            float4 bv = *reinterpret_cast<const float4*>(&Bs[k][tx * 4]);
            float a[4] = {av.x, av.y, av.z, av.w};
            float b[4] = {bv.x, bv.y, bv.z, bv.w};
#pragma unroll
            for (int i = 0; i < 4; ++i)
#pragma unroll
                for (int j = 0; j < 4; ++j)
                    acc[i][j] = fmaf(a[i], b[j], acc[i][j]);
        }
    }
#pragma unroll
    for (int i = 0; i < 4; ++i) {
        int gm = m0 + ty * 4 + i;
#pragma unroll
        for (int j = 0; j < 4; ++j) {
            int gn = n0 + tx * 4 + j;
            if (gn < padN) {
                float v = 0.f;
                if (gn < N) {
                    v = acc[i][j];
                    if (BIAS) v += bias[gn];
                    if (RELU) v = fmaxf(v, 0.f);
                }
                C[(size_t)gm * ldc + gn] = v;
            }
        }
    }
}

template<int VECA, int VECB>
__global__ __launch_bounds__(256)
void gemm_k(const float* __restrict__ A, int lda, int K,
            const float* __restrict__ W, int N,
            float* __restrict__ C, int ldc, int padN, int tiles_n)
{
    __shared__ float As[16][68];
    __shared__ float Bs[16][68];
    const int t = blockIdx.x;
    gemm_tile_core<VECA, VECB, 0, 0>(
        A, lda, K, W, N, nullptr, C, ldc, padN,
        (t / tiles_n) * 64, (t % tiles_n) * 64, As, Bs, threadIdx.x);
}

// -------- K1: emb GEMM tiles (blocks<399) + sparse prep (blocks>=399) -------
__global__ __launch_bounds__(256)
void prep_emb_k(const float* __restrict__ x,
                const float* __restrict__ emb_w, const float* __restrict__ emb_b,
                const float* __restrict__ adj,
                float2* __restrict__ pairs, int2* __restrict__ cnts,
                float* __restrict__ h0)
{
    __shared__ float As[16][68];
    __shared__ float Bs[16][68];
    __shared__ int c0s[NN], c1s[NN];
    const int tid = threadIdx.x;
    if (blockIdx.x < 399) {
        const int t = blockIdx.x;
        gemm_tile_core<0, 0, 1, 1>(
            x, 75, 75, emb_w, 150, emb_b, h0, 152, 152,
            (t / 3) * 64, (t % 3) * 64, As, Bs, tid);
    } else {
        const int b = blockIdx.x - 399;
        for (int i = tid; i < NN; i += 256) { c0s[i] = 0; c1s[i] = 0; }
        __syncthreads();
        const float* adjb = adj + (size_t)b * NN * NN;
        float2* pbg = pairs + (size_t)b * NN * NPAIR;
        for (int q = tid; q < NN * NN; q += 256) {
            int i = q / NN, j = q - i * NN;
            float a = adjb[q];
            if (a > 1e-5f) {
                int s = atomicAdd(&c0s[i], 1);
                pbg[i * NPAIR + s] = make_float2(a, __int_as_float(j));
            } else if (a > 0.f) {
                int s = atomicAdd(&c1s[i], 1);
                pbg[i * NPAIR + (NPAIR - 1) - s] = make_float2(a, __int_as_float(j));
            }
        }
        __syncthreads();
        for (int i = tid; i < NN; i += 256)
            cnts[b * NN + i] = make_int2(c0s[i], c1s[i]);
    }
}

// -------- spmm: one wave per row, GRP*64 cols; 2*GRP gathers in flight ------
template<int GRP>
__global__ __launch_bounds__(256)
void spmm_k(const float* __restrict__ t, int ld, int N,
            const float* __restrict__ bias,
            const float2* __restrict__ pairs, const int2* __restrict__ cnts,
            float* __restrict__ y)
{
    const int wave = threadIdx.x >> 6, lane = threadIdx.x & 63;
    const int r = blockIdx.x * 4 + wave;        // 0..8511
    const int b = r / NN;
    int  c[GRP], sc[GRP];
#pragma unroll
    for (int u = 0; u < GRP; ++u) {
        c[u] = u * 64 + lane;
        sc[u] = min(c[u], N - 1);               // clamp for safe loads
    }
    const float2* pb = pairs + (size_t)r * NPAIR;
    const float4* pq = reinterpret_cast<const float4*>(pb);
    const int2 cc = cnts[r];
    const float* tb = t + (size_t)b * NN * ld;

    float a0[GRP], a1[GRP];
#pragma unroll
    for (int u = 0; u < GRP; ++u) { a0[u] = 0.f; a1[u] = 0.f; }
    int q = 0;
    for (; q + 2 <= cc.x; q += 2) {             // 2 pairs -> 2*GRP loads in flight
        float4 p2 = pq[q >> 1];
        const float* r0 = tb + (size_t)__float_as_int(p2.y) * ld;
        const float* r1 = tb + (size_t)__float_as_int(p2.w) * ld;
#pragma unroll
        for (int u = 0; u < GRP; ++u) {
            a0[u] = fmaf(p2.x, r0[sc[u]], a0[u]);
            a1[u] = fmaf(p2.z, r1[sc[u]], a1[u]);
        }
    }
    if (q < cc.x) {
        float2 f = pb[q];
        const float* r0 = tb + (size_t)__float_as_int(f.y) * ld;
#pragma unroll
        for (int u = 0; u < GRP; ++u) a0[u] = fmaf(f.x, r0[sc[u]], a0[u]);
    }
    for (int v = 0; v < cc.y; ++v) {            // tiny-weight tail (spmm only)
        float2 f = pb[(NPAIR - 1) - v];
        const float* r0 = tb + (size_t)__float_as_int(f.y) * ld;
#pragma unroll
        for (int u = 0; u < GRP; ++u) a0[u] = fmaf(f.x, r0[sc[u]], a0[u]);
    }
#pragma unroll
    for (int u = 0; u < GRP; ++u)
        if (c[u] < N)
            y[(size_t)r * ld + c[u]] = fmaxf(a0[u] + a1[u] + bias[c[u]], 0.f);
}

// -------- pool: p[r,col] = max over front nbrs j of y[j,col] (y>=0) ---------
template<int GRP>
__global__ __launch_bounds__(256)
void pool_k(const float* __restrict__ y, int ld, int N,
            const float2* __restrict__ pairs, const int2* __restrict__ cnts,
            float* __restrict__ p)
{
    const int wave = threadIdx.x >> 6, lane = threadIdx.x & 63;
    const int r = blockIdx.x * 4 + wave;
    const int b = r / NN;
    int  c[GRP], sc[GRP];
#pragma unroll
    for (int u = 0; u < GRP; ++u) {
        c[u] = u * 64 + lane;
        sc[u] = min(c[u], N - 1);
    }
    const float2* pb = pairs + (size_t)r * NPAIR;
    const float4* pq = reinterpret_cast<const float4*>(pb);
    const int cx = cnts[r].x;
    const float* yb = y + (size_t)b * NN * ld;

    float m0[GRP], m1[GRP];
#pragma unroll
    for (int u = 0; u < GRP; ++u) { m0[u] = 0.f; m1[u] = 0.f; }
    int q = 0;
    for (; q + 2 <= cx; q += 2) {
        float4 p2 = pq[q >> 1];
        const float* r0 = yb + (size_t)__float_as_int(p2.y) * ld;
        const float* r1 = yb + (size_t)__float_as_int(p2.w) * ld;
#pragma unroll
        for (int u = 0; u < GRP; ++u) {
            m0[u] = fmaxf(m0[u], r0[sc[u]]);
            m1[u] = fmaxf(m1[u], r1[sc[u]]);
        }
    }
    if (q < cx) {
        const float* r0 = yb + (size_t)__float_as_int(pb[q].y) * ld;
#pragma unroll
        for (int u = 0; u < GRP; ++u) m0[u] = fmaxf(m0[u], r0[sc[u]]);
    }
#pragma unroll
    for (int u = 0; u < GRP; ++u)
        if (c[u] < N)
            p[(size_t)r * ld + c[u]] = fmaxf(m0[u], m1[u]);
}

// -------- two-hop y-row: y[j, c(u)] = relu(bi[u] + sum_k a_jk t[k, c(u)]) ---
template<int GRP>
__device__ __forceinline__ void twohop_yrow(
    const float* __restrict__ tb, int ld,
    const float2* __restrict__ pbJ, int2 cj,
    const float* bi, const int* sc, float* yv)
{
    const float4* pqJ = reinterpret_cast<const float4*>(pbJ);
    float a0[GRP], a1[GRP];
#pragma unroll
    for (int u = 0; u < GRP; ++u) { a0[u] = 0.f; a1[u] = 0.f; }
    int q = 0;
    for (; q + 2 <= cj.x; q += 2) {
        float4 p2 = pqJ[q >> 1];
        const float* r0 = tb + (size_t)__float_as_int(p2.y) * ld;
        const float* r1 = tb + (size_t)__float_as_int(p2.w) * ld;
#pragma unroll
        for (int u = 0; u < GRP; ++u) {
            a0[u] = fmaf(p2.x, r0[sc[u]], a0[u]);
            a1[u] = fmaf(p2.z, r1[sc[u]], a1[u]);
        }
    }
    if (q < cj.x) {
        float2 f = pbJ[q];
        const float* r0 = tb + (size_t)__float_as_int(f.y) * ld;
#pragma unroll
        for (int u = 0; u < GRP; ++u) a0[u] = fmaf(f.x, r0[sc[u]], a0[u]);
    }
    for (int v = 0; v < cj.y; ++v) {
        float2 f = pbJ[(NPAIR - 1) - v];
        const float* r0 = tb + (size_t)__float_as_int(f.y) * ld;
#pragma unroll
        for (int u = 0; u < GRP; ++u) a0[u] = fmaf(f.x, r0[sc[u]], a0[u]);
    }
#pragma unroll
    for (int u = 0; u < GRP; ++u)
        yv[u] = fmaxf(a0[u] + a1[u] + bi[u], 0.f);
}

// -------- twohop2: p[r,c] = max_{j in front(r)} relu(b_c + sum a_j. t[.,c]) -
template<int GRP>
__global__ __launch_bounds__(256)
void twohop_pool_k(const float* __restrict__ t, int ld, int N,
                   const float* __restrict__ bias,
                   const float2* __restrict__ pairs,
                   const int2* __restrict__ cnts,
                   float* __restrict__ p)
{
    const int wave = threadIdx.x >> 6, lane = threadIdx.x & 63;
    const int r = blockIdx.x * 4 + wave;        // 0..8511
    const int b = r / NN;
    const int bbase = b * NN;
    int  c[GRP], sc[GRP];
    float bi[GRP];
#pragma unroll
    for (int u = 0; u < GRP; ++u) {
        c[u] = u * 64 + lane;
        sc[u] = min(c[u], N - 1);
        bi[u] = (c[u] < N) ? bias[c[u]] : 0.f;
    }
    const float2* pbR = pairs + (size_t)r * NPAIR;
    const int cxR = cnts[r].x;                  // pool uses front only
    const float* tb = t + (size_t)bbase * ld;

    float m[GRP];
#pragma unroll
    for (int u = 0; u < GRP; ++u) m[u] = 0.f;
    for (int q = 0; q < cxR; ++q) {
        const int j = __float_as_int(pbR[q].y);
        const int gj = bbase + j;
        float yv[GRP];
        twohop_yrow<GRP>(tb, ld, pairs + (size_t)gj * NPAIR, cnts[gj],
                         bi, sc, yv);
#pragma unroll
        for (int u = 0; u < GRP; ++u) m[u] = fmaxf(m[u], yv[u]);
    }
#pragma unroll
    for (int u = 0; u < GRP; ++u)
        if (c[u] < N)
            p[(size_t)r * ld + c[u]] = m[u];
}

// -------- twohop3+t4: t4[r] = sum_c p3[r,c]*gc4_w[c], p3 two-hop ------------
__global__ __launch_bounds__(256)
void twohop_t4_k(const float* __restrict__ t, int ld, int N,  // ld 76, N 75
                 const float* __restrict__ bias,
                 const float2* __restrict__ pairs,
                 const int2* __restrict__ cnts,
                 const float* __restrict__ gc4_w,
                 float* __restrict__ t4)
{
    const int wave = threadIdx.x >> 6, lane = threadIdx.x & 63;
    const int r = blockIdx.x * 4 + wave;        // 0..8511
    const int b = r / NN;
    const int bbase = b * NN;
    int  c[2], sc[2];
    float bi[2], gw[2];
#pragma unroll
    for (int u = 0; u < 2; ++u) {
        c[u] = u * 64 + lane;
        sc[u] = min(c[u], N - 1);
        bi[u] = (c[u] < N) ? bias[c[u]] : 0.f;
        gw[u] = (c[u] < N) ? gc4_w[c[u]] : 0.f;
    }
    const float2* pbR = pairs + (size_t)r * NPAIR;
    const int cxR = cnts[r].x;
    const float* tb = t + (size_t)bbase * ld;

    float m[2] = {0.f, 0.f};
    for (int q = 0; q < cxR; ++q) {
        const int j = __float_as_int(pbR[q].y);
        const int gj = bbase + j;
        float yv[2];
        twohop_yrow<2>(tb, ld, pairs + (size_t)gj * NPAIR, cnts[gj],
                       bi, sc, yv);
        m[0] = fmaxf(m[0], yv[0]);
        m[1] = fmaxf(m[1], yv[1]);
    }
    float v = m[0] * gw[0] + m[1] * gw[1];
#pragma unroll
    for (int off = 32; off; off >>= 1) v += __shfl_xor(v, off, 64);
    if (lane == 0) t4[r] = v;
}

// -------- tail: y4 = relu(A@t4+b4); fc1; fin; sigmoid (64 blocks, tiny) -----
__global__ __launch_bounds__(256)
void tail_k(const float* __restrict__ t4g,  // 8512
            const float2* __restrict__ pairs, const int2* __restrict__ cnts,
            const float* __restrict__ gc4_b,
            const float* __restrict__ fc1_w, const float* __restrict__ fc1_b,
            const float* __restrict__ fin_w, const float* __restrict__ fin_b,
            float* __restrict__ out)
{
    const int b = blockIdx.x, tid = threadIdx.x;
    __shared__ float t4S[NN], y4S[NN], rS[3];
    if (tid < NN) t4S[tid] = t4g[b * NN + tid];
    __syncthreads();
    if (tid < NN) {
        const float2* pb = pairs + ((size_t)b * NN + tid) * NPAIR;
        int2 c = cnts[b * NN + tid];
        float s = gc4_b[0];
        for (int q = 0; q < c.x; ++q) {
            float2 f = pb[q];
            s = fmaf(f.x, t4S[__float_as_int(f.y)], s);
        }
        for (int q = 0; q < c.y; ++q) {
            float2 f = pb[(NPAIR - 1) - q];
            s = fmaf(f.x, t4S[__float_as_int(f.y)], s);
        }
        y4S[tid] = fmaxf(s, 0.f);
    }
    __syncthreads();
    if (tid < 3) {
        float s = fc1_b[tid];
        for (int j = 0; j < 132; ++j)
            s = fmaf(y4S[1 + j], fc1_w[j * 3 + tid], s);
        rS[tid] = s;
    }
    __syncthreads();
    if (tid == 0) {
        float z = fin_b[0] + y4S[0] * fin_w[0] + rS[0] * fin_w[1]
                + rS[1] * fin_w[2] + rS[2] * fin_w[3];
        out[b] = 1.f / (1.f + expf(-z));
    }
}

extern "C" void kernel_launch(void* const* d_in, const int* in_sizes, int n_in,
                              void* d_out, int out_size, void* d_ws, size_t ws_size,
                              hipStream_t stream)
{
    const float* x     = (const float*)d_in[0];
    const float* adj   = (const float*)d_in[1];
    const float* emb_w = (const float*)d_in[2];
    const float* emb_b = (const float*)d_in[3];
    const float* gc1_w = (const float*)d_in[4];
    const float* gc1_b = (const float*)d_in[5];
    const float* gc2_w = (const float*)d_in[6];
    const float* gc2_b = (const float*)d_in[7];
    const float* gc3_w = (const float*)d_in[8];
    const float* gc3_b = (const float*)d_in[9];
    const float* gc4_w = (const float*)d_in[10];
    const float* gc4_b = (const float*)d_in[11];
    const float* fc1_w = (const float*)d_in[12];
    const float* fc1_b = (const float*)d_in[13];
    const float* fin_w = (const float*)d_in[14];
    const float* fin_b = (const float*)d_in[15];
    float* out = (float*)d_out;

    // ws: pairs 4.36MB | cnts 68KB | bA 8.72MB | bB 8.72MB | bC 8.72MB | t4
    const long MR = 64L * NN;                    // 8512
    float2* pairs = (float2*)d_ws;
    int2*   cnts  = (int2*)(pairs + MR * NPAIR);
    float*  bA    = (float*)(cnts + MR);
    float*  bB    = bA + MR * 256;
    float*  bC    = bB + MR * 256;
    float*  t4    = bC + MR * 256;               // 8512 floats

    // K1: emb GEMM (399 tiles) -> bC (h0, ld 152) + sparse prep (64 graphs)
    prep_emb_k<<<463, 256, 0, stream>>>(x, emb_w, emb_b, adj, pairs, cnts, bC);
    // K2: t1 = h0 @ gc1_w -> bA ld 256
    gemm_k<1, 1><<<532, 256, 0, stream>>>(bC, 152, 150, gc1_w, 256,
                                          bA, 256, 256, 4);
    // K3: y1 -> bB (one wave per row, 256 cols)
    spmm_k<4><<<2128, 256, 0, stream>>>(bA, 256, 256, gc1_b, pairs, cnts, bB);
    // K4: p1 -> bC
    pool_k<4><<<2128, 256, 0, stream>>>(bB, 256, 256, pairs, cnts, bC);
    // K5: t2 = p1 @ gc2_w -> bA ld 128
    gemm_k<1, 1><<<266, 256, 0, stream>>>(bC, 256, 256, gc2_w, 128,
                                          bA, 128, 128, 2);
    // K6: p2 = twohop(t2) -> bB ld 128  (replaces spmm2+pool2)
    twohop_pool_k<2><<<2128, 256, 0, stream>>>(bA, 128, 128, gc2_b,
                                               pairs, cnts, bB);
    // K7: t3 = p2 @ gc3_w -> bC ld 76 (padN=76 zero-fills col 75)
    gemm_k<1, 0><<<266, 256, 0, stream>>>(bB, 128, 128, gc3_w, 75,
                                          bC, 76, 76, 2);
    // K8: t4[r] = twohop-pool3(t3)[r] . gc4_w  (replaces spmm3+pool3+t4)
    twohop_t4_k<<<2128, 256, 0, stream>>>(bC, 76, 75, gc3_b,
                                          pairs, cnts, gc4_w, t4);
    // K9: tail
    tail_k<<<64, 256, 0, stream>>>(t4, pairs, cnts, gc4_b,
                                   fc1_w, fc1_b, fin_w, fin_b, out);
}

// Round 12
// 223.609 us; speedup vs baseline: 1.5175x; 1.5175x over previous
//
#include <hip/hip_runtime.h>
#include <math.h>

// ---------------------------------------------------------------------------
// B=64 graphs, NN=133 nodes. 11 plain launches (best-known structure, R10 =
// 241.7us, + parallel ballot prep + 4-chain MLP in sparse kernels):
//  K1 prep_emb : blocks<399 -> emb GEMM tiles; blocks>=399 -> ballot prep,
//                one wave per adjacency row (2128 prep blocks)
//  K2 gemm1 t1=h0@gc1_w (532 tiles)       K3 spmm1 (GRP=4, 1 wave/row)
//  K4 pool1 (GRP=4)                       K5 gemm2 (266)
//  K6 spmm2 (GRP=2)                       K7 pool2 (GRP=2)
//  K8 gemm3 (266)                         K9 spmm3 (GRP=2, N=75 masked)
//  K10 t4_k: t4[r]=pool3(y3)[r].gc4_w, one wave/row
//  K11 tail: y4 sparse from t4 + fc1 + fin -> sigmoid (64 blocks)
// Sparse lists per row: front = a>1e-5 (spmm+pool), back = 0<a<=1e-5 (spmm
// only). Sparse kernels: one wave per adjacency row; pair lists read as
// float4 (2 pairs), 4 pairs per step -> 4 independent gather chains in
// flight (R11 lesson: dependent-gather chain length is the latency wall).
// ---------------------------------------------------------------------------

#define NN 133
#define NPAIR 64

// ---------------- GEMM core: one 64x64 tile, prefetch-pipelined -------------
template<int VECA, int VECB, int RELU, int BIAS>
__device__ __forceinline__ void gemm_tile_core(
    const float* __restrict__ A, int lda, int K,
    const float* __restrict__ W, int N,
    const float* __restrict__ bias,
    float* __restrict__ C, int ldc, int padN,
    int m0, int n0, float (*As)[68], float (*Bs)[68], int tid)
{
    const int la_m = tid >> 2, la_k = (tid & 3) * 4;   // A: 64 rows x 4 float4
    const int lb_k = tid >> 4, lb_n = (tid & 15) * 4;  // B: 16 k-rows x 16 f4
    const int tx = tid & 15, ty = tid >> 4;
    const int r = m0 + la_m;

    float pa[4], pb[4];
    if (VECA) {
        float4 v = *reinterpret_cast<const float4*>(A + (size_t)r * lda + la_k);
        pa[0] = v.x; pa[1] = v.y; pa[2] = v.z; pa[3] = v.w;
    } else {
#pragma unroll
        for (int j = 0; j < 4; ++j) {
            int gk = la_k + j;
            pa[j] = (gk < K) ? A[(size_t)r * lda + gk] : 0.f;
        }
    }
    if (VECB) {
        if (lb_k < K) {
            float4 v = *reinterpret_cast<const float4*>(
                W + (size_t)lb_k * N + n0 + lb_n);
            pb[0] = v.x; pb[1] = v.y; pb[2] = v.z; pb[3] = v.w;
        } else { pb[0] = pb[1] = pb[2] = pb[3] = 0.f; }
    } else {
#pragma unroll
        for (int j = 0; j < 4; ++j) {
            int gn = n0 + lb_n + j;
            pb[j] = (lb_k < K && gn < N) ? W[(size_t)lb_k * N + gn] : 0.f;
        }
    }

    float acc[4][4] = {};
    for (int k0 = 0; k0 < K; k0 += 16) {
        __syncthreads();
#pragma unroll
        for (int j = 0; j < 4; ++j) As[la_k + j][la_m] = pa[j];
        *reinterpret_cast<float4*>(&Bs[lb_k][lb_n]) =
            make_float4(pb[0], pb[1], pb[2], pb[3]);
        __syncthreads();
        const int kn = k0 + 16;
        if (kn < K) {   // prefetch next k-tile (overlaps FMA block)
            if (VECA) {
                float4 v = *reinterpret_cast<const float4*>(
                    A + (size_t)r * lda + kn + la_k);
                pa[0] = v.x; pa[1] = v.y; pa[2] = v.z; pa[3] = v.w;
            } else {
#pragma unroll
                for (int j = 0; j < 4; ++j) {
                    int gk = kn + la_k + j;
                    pa[j] = (gk < K) ? A[(size_t)r * lda + gk] : 0.f;
                }
            }
            int gk = kn + lb_k;
            if (VECB) {
                if (gk < K) {
                    float4 v = *reinterpret_cast<const float4*>(
                        W + (size_t)gk * N + n0 + lb_n);
                    pb[0] = v.x; pb[1] = v.y; pb[2] = v.z; pb[3] = v.w;
                } else { pb[0] = pb[1] = pb[2] = pb[3] = 0.f; }
            } else {
#pragma unroll
                for (int j = 0; j < 4; ++j) {
                    int gn = n0 + lb_n + j;
                    pb[j] = (gk < K && gn < N) ? W[(size_t)gk * N + gn] : 0.f;
                }
            }
        }
#pragma unroll
        for (int k = 0; k < 16; ++k) {
            float4 av = *reinterpret_cast<const float4*>(&As[k][ty * 4]);
            float4 bv = *reinterpret_cast<const float4*>(&Bs[k][tx * 4]);
            float a[4] = {av.x, av.y, av.z, av.w};
            float b[4] = {bv.x, bv.y, bv.z, bv.w};
#pragma unroll
            for (int i = 0; i < 4; ++i)
#pragma unroll
                for (int j = 0; j < 4; ++j)
                    acc[i][j] = fmaf(a[i], b[j], acc[i][j]);
        }
    }
#pragma unroll
    for (int i = 0; i < 4; ++i) {
        int gm = m0 + ty * 4 + i;
#pragma unroll
        for (int j = 0; j < 4; ++j) {
            int gn = n0 + tx * 4 + j;
            if (gn < padN) {
                float v = 0.f;
                if (gn < N) {
                    v = acc[i][j];
                    if (BIAS) v += bias[gn];
                    if (RELU) v = fmaxf(v, 0.f);
                }
                C[(size_t)gm * ldc + gn] = v;
            }
        }
    }
}

template<int VECA, int VECB>
__global__ __launch_bounds__(256)
void gemm_k(const float* __restrict__ A, int lda, int K,
            const float* __restrict__ W, int N,
            float* __restrict__ C, int ldc, int padN, int tiles_n)
{
    __shared__ float As[16][68];
    __shared__ float Bs[16][68];
    const int t = blockIdx.x;
    gemm_tile_core<VECA, VECB, 0, 0>(
        A, lda, K, W, N, nullptr, C, ldc, padN,
        (t / tiles_n) * 64, (t % tiles_n) * 64, As, Bs, threadIdx.x);
}

// -------- K1: emb GEMM tiles (blocks<399) + ballot prep (blocks>=399) -------
// Prep: one wave per adjacency row; ballot-compacted front/back lists.
__global__ __launch_bounds__(256)
void prep_emb_k(const float* __restrict__ x,
                const float* __restrict__ emb_w, const float* __restrict__ emb_b,
                const float* __restrict__ adj,
                float2* __restrict__ pairs, int2* __restrict__ cnts,
                float* __restrict__ h0)
{
    __shared__ float As[16][68];
    __shared__ float Bs[16][68];
    const int tid = threadIdx.x;
    if (blockIdx.x < 399) {
        const int t = blockIdx.x;
        gemm_tile_core<0, 0, 1, 1>(
            x, 75, 75, emb_w, 150, emb_b, h0, 152, 152,
            (t / 3) * 64, (t % 3) * 64, As, Bs, tid);
    } else {
        const int wave = tid >> 6, lane = tid & 63;
        const int r = (blockIdx.x - 399) * 4 + wave;   // 0..8511
        const float* ar = adj + (size_t)r * NN;
        float2* pb = pairs + (size_t)r * NPAIR;
        const unsigned long long lt = (1ull << lane) - 1ull;
        int base0 = 0, base1 = 0;
#pragma unroll
        for (int s = 0; s < 3; ++s) {
            const int j = lane + 64 * s;
            const float a = (j < NN) ? ar[j] : 0.f;
            const bool f = a > 1e-5f;
            const bool g = (a > 0.f) && !f;
            const unsigned long long mf = __ballot(f);
            const unsigned long long mg = __ballot(g);
            if (f) pb[base0 + __popcll(mf & lt)] =
                       make_float2(a, __int_as_float(j));
            if (g) pb[(NPAIR - 1) - (base1 + __popcll(mg & lt))] =
                       make_float2(a, __int_as_float(j));
            base0 += __popcll(mf);
            base1 += __popcll(mg);
        }
        if (lane == 0) cnts[r] = make_int2(base0, base1);
    }
}

// -------- spmm: one wave per row, GRP*64 cols; 4 gather chains per GRP ------
template<int GRP>
__global__ __launch_bounds__(256)
void spmm_k(const float* __restrict__ t, int ld, int N,
            const float* __restrict__ bias,
            const float2* __restrict__ pairs, const int2* __restrict__ cnts,
            float* __restrict__ y)
{
    const int wave = threadIdx.x >> 6, lane = threadIdx.x & 63;
    const int r = blockIdx.x * 4 + wave;        // 0..8511
    const int b = r / NN;
    int  c[GRP], sc[GRP];
#pragma unroll
    for (int u = 0; u < GRP; ++u) {
        c[u] = u * 64 + lane;
        sc[u] = min(c[u], N - 1);               // clamp for safe loads
    }
    const float2* pb = pairs + (size_t)r * NPAIR;
    const float4* pq = reinterpret_cast<const float4*>(pb);
    const int2 cc = cnts[r];
    const float* tb = t + (size_t)b * NN * ld;

    float a0[GRP], a1[GRP], a2[GRP], a3[GRP];
#pragma unroll
    for (int u = 0; u < GRP; ++u) { a0[u] = a1[u] = a2[u] = a3[u] = 0.f; }
    int q = 0;
    for (; q + 4 <= cc.x; q += 4) {             // 4 independent gather chains
        float4 pA = pq[q >> 1], pB = pq[(q >> 1) + 1];
        const float* r0 = tb + (size_t)__float_as_int(pA.y) * ld;
        const float* r1 = tb + (size_t)__float_as_int(pA.w) * ld;
        const float* r2 = tb + (size_t)__float_as_int(pB.y) * ld;
        const float* r3 = tb + (size_t)__float_as_int(pB.w) * ld;
#pragma unroll
        for (int u = 0; u < GRP; ++u) {
            a0[u] = fmaf(pA.x, r0[sc[u]], a0[u]);
            a1[u] = fmaf(pA.z, r1[sc[u]], a1[u]);
            a2[u] = fmaf(pB.x, r2[sc[u]], a2[u]);
            a3[u] = fmaf(pB.z, r3[sc[u]], a3[u]);
        }
    }
    for (; q < cc.x; ++q) {
        float2 f = pb[q];
        const float* r0 = tb + (size_t)__float_as_int(f.y) * ld;
#pragma unroll
        for (int u = 0; u < GRP; ++u) a0[u] = fmaf(f.x, r0[sc[u]], a0[u]);
    }
    for (int v = 0; v < cc.y; ++v) {            // tiny-weight tail (spmm only)
        float2 f = pb[(NPAIR - 1) - v];
        const float* r0 = tb + (size_t)__float_as_int(f.y) * ld;
#pragma unroll
        for (int u = 0; u < GRP; ++u) a0[u] = fmaf(f.x, r0[sc[u]], a0[u]);
    }
#pragma unroll
    for (int u = 0; u < GRP; ++u)
        if (c[u] < N)
            y[(size_t)r * ld + c[u]] =
                fmaxf((a0[u] + a1[u]) + (a2[u] + a3[u]) + bias[c[u]], 0.f);
}

// -------- pool: p[r,col] = max over front nbrs j of y[j,col] (y>=0) ---------
template<int GRP>
__global__ __launch_bounds__(256)
void pool_k(const float* __restrict__ y, int ld, int N,
            const float2* __restrict__ pairs, const int2* __restrict__ cnts,
            float* __restrict__ p)
{
    const int wave = threadIdx.x >> 6, lane = threadIdx.x & 63;
    const int r = blockIdx.x * 4 + wave;
    const int b = r / NN;
    int  c[GRP], sc[GRP];
#pragma unroll
    for (int u = 0; u < GRP; ++u) {
        c[u] = u * 64 + lane;
        sc[u] = min(c[u], N - 1);
    }
    const float2* pb = pairs + (size_t)r * NPAIR;
    const float4* pq = reinterpret_cast<const float4*>(pb);
    const int cx = cnts[r].x;
    const float* yb = y + (size_t)b * NN * ld;

    float m0[GRP], m1[GRP], m2[GRP], m3[GRP];
#pragma unroll
    for (int u = 0; u < GRP; ++u) { m0[u] = m1[u] = m2[u] = m3[u] = 0.f; }
    int q = 0;
    for (; q + 4 <= cx; q += 4) {               // 4 independent gather chains
        float4 pA = pq[q >> 1], pB = pq[(q >> 1) + 1];
        const float* r0 = yb + (size_t)__float_as_int(pA.y) * ld;
        const float* r1 = yb + (size_t)__float_as_int(pA.w) * ld;
        const float* r2 = yb + (size_t)__float_as_int(pB.y) * ld;
        const float* r3 = yb + (size_t)__float_as_int(pB.w) * ld;
#pragma unroll
        for (int u = 0; u < GRP; ++u) {
            m0[u] = fmaxf(m0[u], r0[sc[u]]);
            m1[u] = fmaxf(m1[u], r1[sc[u]]);
            m2[u] = fmaxf(m2[u], r2[sc[u]]);
            m3[u] = fmaxf(m3[u], r3[sc[u]]);
        }
    }
    for (; q < cx; ++q) {
        const float* r0 = yb + (size_t)__float_as_int(pb[q].y) * ld;
#pragma unroll
        for (int u = 0; u < GRP; ++u) m0[u] = fmaxf(m0[u], r0[sc[u]]);
    }
#pragma unroll
    for (int u = 0; u < GRP; ++u)
        if (c[u] < N)
            p[(size_t)r * ld + c[u]] =
                fmaxf(fmaxf(m0[u], m1[u]), fmaxf(m2[u], m3[u]));
}

// -------- t4: t4[r] = dot(pool3(y3)[r,0:75], gc4_w), one wave per row -------
__global__ __launch_bounds__(256)
void t4_k(const float* __restrict__ y3,   // ld 76, 75 valid cols
          const float2* __restrict__ pairs, const int2* __restrict__ cnts,
          const float* __restrict__ gc4_w,
          float* __restrict__ t4)         // 8512
{
    const int wave = threadIdx.x >> 6, lane = threadIdx.x & 63;
    const int r = blockIdx.x * 4 + wave;        // 0..8511
    const int b = r / NN;
    const float* yb = y3 + (size_t)b * NN * 76;
    const float2* pb = pairs + (size_t)r * NPAIR;
    const float4* pq = reinterpret_cast<const float4*>(pb);
    const int cx = cnts[r].x;
    const float gw0 = gc4_w[lane];                       // lane<=63<75 valid
    const float gw1 = (lane < 11) ? gc4_w[64 + lane] : 0.f;
    const int c2 = 64 + min(lane, 10);                   // safe 2nd col

    float m0a = 0.f, m1a = 0.f, m0b = 0.f, m1b = 0.f;
    float m0c = 0.f, m1c = 0.f, m0d = 0.f, m1d = 0.f;
    int q = 0;
    for (; q + 4 <= cx; q += 4) {               // 4 independent gather chains
        float4 pA = pq[q >> 1], pB = pq[(q >> 1) + 1];
        const float* r0 = yb + (size_t)__float_as_int(pA.y) * 76;
        const float* r1 = yb + (size_t)__float_as_int(pA.w) * 76;
        const float* r2 = yb + (size_t)__float_as_int(pB.y) * 76;
        const float* r3 = yb + (size_t)__float_as_int(pB.w) * 76;
        m0a = fmaxf(m0a, r0[lane]); m1a = fmaxf(m1a, r0[c2]);
        m0b = fmaxf(m0b, r1[lane]); m1b = fmaxf(m1b, r1[c2]);
        m0c = fmaxf(m0c, r2[lane]); m1c = fmaxf(m1c, r2[c2]);
        m0d = fmaxf(m0d, r3[lane]); m1d = fmaxf(m1d, r3[c2]);
    }
    for (; q < cx; ++q) {
        const float* r0 = yb + (size_t)__float_as_int(pb[q].y) * 76;
        m0a = fmaxf(m0a, r0[lane]); m1a = fmaxf(m1a, r0[c2]);
    }
    float m0 = fmaxf(fmaxf(m0a, m0b), fmaxf(m0c, m0d));
    float m1 = fmaxf(fmaxf(m1a, m1b), fmaxf(m1c, m1d));
    float v = m0 * gw0 + m1 * gw1;
#pragma unroll
    for (int off = 32; off; off >>= 1) v += __shfl_xor(v, off, 64);
    if (lane == 0) t4[r] = v;
}

// -------- tail: y4 = relu(A@t4+b4); fc1; fin; sigmoid (64 blocks, tiny) -----
__global__ __launch_bounds__(256)
void tail_k(const float* __restrict__ t4g,  // 8512
            const float2* __restrict__ pairs, const int2* __restrict__ cnts,
            const float* __restrict__ gc4_b,
            const float* __restrict__ fc1_w, const float* __restrict__ fc1_b,
            const float* __restrict__ fin_w, const float* __restrict__ fin_b,
            float* __restrict__ out)
{
    const int b = blockIdx.x, tid = threadIdx.x;
    __shared__ float t4S[NN], y4S[NN], rS[3];
    if (tid < NN) t4S[tid] = t4g[b * NN + tid];
    __syncthreads();
    if (tid < NN) {
        const float2* pb = pairs + ((size_t)b * NN + tid) * NPAIR;
        int2 c = cnts[b * NN + tid];
        float s = gc4_b[0];
        for (int q = 0; q < c.x; ++q) {
            float2 f = pb[q];
            s = fmaf(f.x, t4S[__float_as_int(f.y)], s);
        }
        for (int q = 0; q < c.y; ++q) {
            float2 f = pb[(NPAIR - 1) - q];
            s = fmaf(f.x, t4S[__float_as_int(f.y)], s);
        }
        y4S[tid] = fmaxf(s, 0.f);
    }
    __syncthreads();
    if (tid < 3) {
        float s = fc1_b[tid];
        for (int j = 0; j < 132; ++j)
            s = fmaf(y4S[1 + j], fc1_w[j * 3 + tid], s);
        rS[tid] = s;
    }
    __syncthreads();
    if (tid == 0) {
        float z = fin_b[0] + y4S[0] * fin_w[0] + rS[0] * fin_w[1]
                + rS[1] * fin_w[2] + rS[2] * fin_w[3];
        out[b] = 1.f / (1.f + expf(-z));
    }
}

extern "C" void kernel_launch(void* const* d_in, const int* in_sizes, int n_in,
                              void* d_out, int out_size, void* d_ws, size_t ws_size,
                              hipStream_t stream)
{
    const float* x     = (const float*)d_in[0];
    const float* adj   = (const float*)d_in[1];
    const float* emb_w = (const float*)d_in[2];
    const float* emb_b = (const float*)d_in[3];
    const float* gc1_w = (const float*)d_in[4];
    const float* gc1_b = (const float*)d_in[5];
    const float* gc2_w = (const float*)d_in[6];
    const float* gc2_b = (const float*)d_in[7];
    const float* gc3_w = (const float*)d_in[8];
    const float* gc3_b = (const float*)d_in[9];
    const float* gc4_w = (const float*)d_in[10];
    const float* gc4_b = (const float*)d_in[11];
    const float* fc1_w = (const float*)d_in[12];
    const float* fc1_b = (const float*)d_in[13];
    const float* fin_w = (const float*)d_in[14];
    const float* fin_b = (const float*)d_in[15];
    float* out = (float*)d_out;

    // ws: pairs 4.36MB | cnts 68KB | bA 8.72MB | bB 8.72MB | bC 8.72MB | t4
    const long MR = 64L * NN;                    // 8512
    float2* pairs = (float2*)d_ws;
    int2*   cnts  = (int2*)(pairs + MR * NPAIR);
    float*  bA    = (float*)(cnts + MR);
    float*  bB    = bA + MR * 256;
    float*  bC    = bB + MR * 256;
    float*  t4    = bC + MR * 256;               // 8512 floats

    // K1: emb GEMM (399 tiles) -> bC (h0, ld 152) + ballot prep (2128 blocks)
    prep_emb_k<<<399 + 2128, 256, 0, stream>>>(x, emb_w, emb_b, adj,
                                               pairs, cnts, bC);
    // K2: t1 = h0 @ gc1_w -> bA ld 256
    gemm_k<1, 1><<<532, 256, 0, stream>>>(bC, 152, 150, gc1_w, 256,
                                          bA, 256, 256, 4);
    // K3: y1 -> bB (one wave per row, 256 cols)
    spmm_k<4><<<2128, 256, 0, stream>>>(bA, 256, 256, gc1_b, pairs, cnts, bB);
    // K4: p1 -> bC
    pool_k<4><<<2128, 256, 0, stream>>>(bB, 256, 256, pairs, cnts, bC);
    // K5: t2 = p1 @ gc2_w -> bA ld 128
    gemm_k<1, 1><<<266, 256, 0, stream>>>(bC, 256, 256, gc2_w, 128,
                                          bA, 128, 128, 2);
    // K6: y2 -> bB
    spmm_k<2><<<2128, 256, 0, stream>>>(bA, 128, 128, gc2_b, pairs, cnts, bB);
    // K7: p2 -> bC
    pool_k<2><<<2128, 256, 0, stream>>>(bB, 128, 128, pairs, cnts, bC);
    // K8: t3 = p2 @ gc3_w -> bA ld 76 (padN=76 zero-fills col 75)
    gemm_k<1, 0><<<266, 256, 0, stream>>>(bC, 128, 128, gc3_w, 75,
                                          bA, 76, 76, 2);
    // K9: y3 -> bB (N=75, second col group masked)
    spmm_k<2><<<2128, 256, 0, stream>>>(bA, 76, 75, gc3_b, pairs, cnts, bB);
    // K10: t4[r] = pool3(y3)[r] . gc4_w  (one wave per row)
    t4_k<<<2128, 256, 0, stream>>>(bB, pairs, cnts, gc4_w, t4);
    // K11: tail
    tail_k<<<64, 256, 0, stream>>>(t4, pairs, cnts, gc4_b,
                                   fc1_w, fc1_b, fin_w, fin_b, out);
}